// Round 5
// baseline (988.855 us; speedup 1.0000x reference)
//
#include <hip/hip_runtime.h>
#include <stdint.h>

#define NN3 262144
#define NN2 65536
#define NN1 16384

typedef __attribute__((ext_vector_type(8))) __bf16 bf16x8;
typedef __attribute__((ext_vector_type(4))) float floatx4;
typedef __attribute__((ext_vector_type(4))) unsigned int uintx4;

static __device__ __forceinline__ float bf2f(unsigned short u) {
    union { unsigned int i; float f; } v; v.i = ((unsigned int)u) << 16; return v.f;
}
static __device__ __forceinline__ unsigned short f2bf(float f) {
    union { float f; unsigned int i; } v; v.f = f;
    unsigned int x = v.i;
    return (unsigned short)((x + 0x7fffu + ((x >> 16) & 1u)) >> 16);
}
static __device__ __forceinline__ bf16x8 zero_bf16x8() {
    bf16x8 z;
#pragma unroll
    for (int i = 0; i < 8; ++i) z[i] = (__bf16)0.0f;
    return z;
}

struct Params {
    const float* features;
    const int* neighs3; const int* neighs2; const int* neighs1;
    const float* w_enc1; const float* b_enc1;
    const float* w_enc2; const float* b_enc2;
    const float* w_enc3; const float* b_enc3;
    const float* w_dec1; const float* b_dec1;
    const float* w_dec2; const float* b_dec2;
    const float* w_head; const float* b_head;
    unsigned short* wb_enc2; unsigned short* wb_enc3;
    unsigned short* wb_dec1; unsigned short* wb_dec2;
    unsigned short* x7p; unsigned short* x6p; unsigned short* x6;
    unsigned short* x7dec; unsigned short* x8dec;
    unsigned int* bar;       // 5 grid-barrier counters, zeroed by init kernel
    float* out;
};

// ---------------- software grid barrier (capture-safe; no coop API) ----------------
// Grid is sized/bounded for guaranteed co-residency: 1024 blocks = 4/CU x 256 CU,
// __launch_bounds__(256,4), 9.9KB LDS. Device-scope release-add + acquire-spin +
// threadfence both sides = the Guideline-16 inter-XCD visibility pattern (same as
// cg::grid_group::sync). Spin bails after 16M polls: a co-residency failure makes
// a WRONG ANSWER (bench feedback), never a dead container.
static __device__ __forceinline__ void gridsync(unsigned int* bar, unsigned int target) {
    __syncthreads();
    if (threadIdx.x == 0) {
        __threadfence();
        __hip_atomic_fetch_add(bar, 1u, __ATOMIC_RELEASE, __HIP_MEMORY_SCOPE_AGENT);
        unsigned int spins = 0;
        while (__hip_atomic_load(bar, __ATOMIC_ACQUIRE, __HIP_MEMORY_SCOPE_AGENT) < target) {
            __builtin_amdgcn_s_sleep(2);
            if (++spins > (1u << 24)) break;   // hang-guard
        }
        __threadfence();
    }
    __syncthreads();
}

__global__ __launch_bounds__(64) void init_bar(unsigned int* bar) {
    if (threadIdx.x < 8) bar[threadIdx.x] = 0u;
}

// ---------------- swizzled weight prep ----------------
//   out[((n*KT + kt)*64 + lane)*8 + e] = w[(n*16 + m)*K + kt*32 + quad*8 + e]
template <int CIN, int COUT>
static __device__ __forceinline__ void prep_swz(const float* __restrict__ w,
                                                unsigned short* __restrict__ out, int g) {
    constexpr int K = 9 * CIN, KT = (K + 31) / 32;
    int n = g / (KT * 512);
    int r = g - n * (KT * 512);
    int kt = r >> 9;
    int q = r & 511;
    int lane = q >> 3, e = q & 7;
    int m = lane & 15, quad = lane >> 4;
    int k = kt * 32 + quad * 8 + e;
    float v = (k < K) ? w[(n * 16 + m) * K + k] : 0.0f;
    out[g] = f2bf(v);
}

// ---------------- stage bodies ----------------

// enc1 + pool1 + folded weight prep. 256 rows/block x 1024 blocks.
static __device__ __forceinline__ void enc1pool_body(const Params& p, int* nsh,
                                                     float* ws, float* bs) {
    int t = threadIdx.x;
    {   // folded swizzled weight prep: 46592 elems over first 182 blocks
        int g = blockIdx.x * 256 + t;
        if (g < 5120) prep_swz<16, 32>(p.w_enc2, p.wb_enc2, g);          // NT=2 KT=5
        else {
            g -= 5120;
            if (g < 18432) prep_swz<32, 64>(p.w_enc3, p.wb_enc3, g);     // NT=4 KT=9
            else {
                g -= 18432;
                if (g < 18432) prep_swz<64, 32>(p.w_dec1, p.wb_dec1, g); // NT=2 KT=18
                else { g -= 18432; if (g < 4608) prep_swz<32, 16>(p.w_dec2, p.wb_dec2, g); }
            }
        }
    }
    if (t < 144) ws[t] = p.w_enc1[t];
    if (t < 16)  bs[t] = p.b_enc1[t];
    int base = blockIdx.x * 256;
    for (int e = t; e < 2304; e += 256)
        nsh[e] = __builtin_nontemporal_load(&p.neighs3[(size_t)base * 9 + e]);
    __syncthreads();
    float f[9];
#pragma unroll
    for (int k = 0; k < 9; ++k) { int j = nsh[t * 9 + k]; f[k] = (j < 0) ? 0.0f : p.features[j]; }
    float v[16];
#pragma unroll
    for (int co = 0; co < 16; ++co) {
        float a = bs[co];
#pragma unroll
        for (int k = 0; k < 9; ++k) a += f[k] * ws[co * 9 + k];
        v[co] = fmaxf(a, 0.0f);
    }
#pragma unroll
    for (int co = 0; co < 16; ++co) {
        v[co] = fmaxf(v[co], __shfl_xor(v[co], 1));
        v[co] = fmaxf(v[co], __shfl_xor(v[co], 2));
    }
    if ((t & 3) == 0) {
        unsigned int ov[8];
#pragma unroll
        for (int h = 0; h < 8; ++h)
            ov[h] = (unsigned int)f2bf(v[2 * h]) | (((unsigned int)f2bf(v[2 * h + 1])) << 16);
        uintx4* dst = (uintx4*)(p.x7p + (size_t)((base + t) >> 2) * 16);
        uintx4 o0 = {ov[0], ov[1], ov[2], ov[3]};
        uintx4 o1 = {ov[4], ov[5], ov[6], ov[7]};
        dst[0] = o0;
        dst[1] = o1;
    }
}

// generic MFMA conv stage; all stages decompose to exactly 1024 blocks.
template <int CIN, int COUT, bool SHIFT, bool POOL, int TILES, int WN>
static __device__ __forceinline__ void conv_body(
    const unsigned short* __restrict__ src, const int* __restrict__ neigh,
    const unsigned short* __restrict__ wb, const float* __restrict__ bias,
    unsigned short* __restrict__ dst, int* nsh)
{
    constexpr int K   = 9 * CIN;
    constexpr int KT  = (K + 31) / 32;
    constexpr int NT  = COUT / 16;
    constexpr int WM  = 4 / WN;
    constexpr int NTW = NT / WN;
    constexpr int ROWS = WM * TILES * 16;
    int t = threadIdx.x;
    int rowbase = blockIdx.x * ROWS;
    for (int e = t; e < ROWS * 9; e += 256) {
        int j = __builtin_nontemporal_load(&neigh[(size_t)rowbase * 9 + e]);
        if (SHIFT) j = (j < 0) ? -1 : (j >> 2);
        nsh[e] = j;
    }
    __syncthreads();
    int lane = t & 63;
    int wave = t >> 6;
    int wm   = wave / WN;
    int wn   = wave - wm * WN;
    int m    = lane & 15;
    int quad = lane >> 4;
    int rbase9[TILES];
#pragma unroll
    for (int tl = 0; tl < TILES; ++tl)
        rbase9[tl] = ((wm * TILES + tl) * 16 + m) * 9;

    floatx4 acc[TILES][NTW];
#pragma unroll
    for (int tl = 0; tl < TILES; ++tl)
#pragma unroll
        for (int n = 0; n < NTW; ++n) acc[tl][n] = (floatx4){0.f, 0.f, 0.f, 0.f};

    auto gatherA = [&](int kt, bf16x8 (&dstA)[TILES]) {
        int k0 = kt * 32 + quad * 8;
#pragma unroll
        for (int tl = 0; tl < TILES; ++tl) {
            dstA[tl] = zero_bf16x8();
            if (k0 < K) {
                int j = nsh[rbase9[tl] + k0 / CIN];
                if (j >= 0) dstA[tl] = *(const bf16x8*)(src + (size_t)j * CIN + (k0 % CIN));
            }
        }
    };

    bf16x8 aC[TILES], aP[TILES];
    gatherA(0, aC);
#pragma unroll
    for (int kt = 0; kt < KT; ++kt) {
        if (kt + 1 < KT) gatherA(kt + 1, aP);   // next gathers in flight over MFMAs
#pragma unroll
        for (int n = 0; n < NTW; ++n) {
            int ng = wn * NTW + n;
            bf16x8 bfrag = *(const bf16x8*)(wb + ((size_t)(ng * KT + kt) * 64 + lane) * 8);
#pragma unroll
            for (int tl = 0; tl < TILES; ++tl)
                acc[tl][n] = __builtin_amdgcn_mfma_f32_16x16x32_bf16(aC[tl], bfrag, acc[tl][n], 0, 0, 0);
        }
#pragma unroll
        for (int tl = 0; tl < TILES; ++tl) aC[tl] = aP[tl];
    }

#pragma unroll
    for (int tl = 0; tl < TILES; ++tl) {
        int rg = wm * TILES + tl;
        if (POOL) {
            int pp = (rowbase >> 2) + rg * 4 + quad;
#pragma unroll
            for (int n = 0; n < NTW; ++n) {
                int cout = (wn * NTW + n) * 16 + m;
                float vm = fmaxf(fmaxf(acc[tl][n][0], acc[tl][n][1]), fmaxf(acc[tl][n][2], acc[tl][n][3]));
                float v  = fmaxf(vm + bias[cout], 0.0f);
                dst[(size_t)pp * COUT + cout] = f2bf(v);
            }
        } else {
            int grow = rowbase + rg * 16 + quad * 4;
#pragma unroll
            for (int n = 0; n < NTW; ++n) {
                int cout = (wn * NTW + n) * 16 + m;
                float bv = bias[cout];
#pragma unroll
                for (int r = 0; r < 4; ++r) {
                    float v = fmaxf(acc[tl][n][r] + bv, 0.0f);
                    dst[(size_t)(grow + r) * COUT + cout] = f2bf(v);
                }
            }
        }
    }
}

// head: Cin=16 bf16 -> 1 fp32, no relu. 256 rows/block x 1024 blocks.
static __device__ __forceinline__ float dot2(unsigned int u, const float* w) {
    return bf2f((unsigned short)(u & 0xffffu)) * w[0] + bf2f((unsigned short)(u >> 16)) * w[1];
}
static __device__ __forceinline__ void head_body(const Params& p, int* nsh, float* ws) {
    int t = threadIdx.x;
    if (t < 144) ws[t] = p.w_head[t];
    int base = blockIdx.x * 256;
    for (int e = t; e < 2304; e += 256)
        nsh[e] = __builtin_nontemporal_load(&p.neighs3[(size_t)base * 9 + e]);
    __syncthreads();
    float acc0 = p.b_head[0];
#pragma unroll
    for (int k = 0; k < 9; ++k) {
        int j0 = nsh[t * 9 + k];
        const float* wp = &ws[k * 16];
        if (j0 >= 0) {
            const uint4* r = (const uint4*)(p.x8dec + (size_t)j0 * 16);
            uint4 r0 = r[0], r1 = r[1];
            acc0 += dot2(r0.x, wp)     + dot2(r0.y, wp + 2)  + dot2(r0.z, wp + 4)  + dot2(r0.w, wp + 6);
            acc0 += dot2(r1.x, wp + 8) + dot2(r1.y, wp + 10) + dot2(r1.z, wp + 12) + dot2(r1.w, wp + 14);
        }
    }
    p.out[base + t] = acc0;
}

// ---------------- fused kernel: 6 stages, 5 software grid barriers ----------------
// Per-stage decomposition identical to the 6-kernel version (each stage = 1024
// blocks x 1 iteration). The only change vs round 3: kernel boundaries (launch +
// drain + cache ops) -> in-kernel barriers.
__global__ __launch_bounds__(256, 4) void fused_kernel(Params p) {
    __shared__ __align__(16) int nsh[2304];
    __shared__ float ws[144];
    __shared__ float bs[16];

    enc1pool_body(p, nsh, ws, bs);                                                 // -> x7p
    gridsync(p.bar + 0, 1024);
    conv_body<16, 32, false, true,  2, 2>(p.x7p,   p.neighs2, p.wb_enc2, p.b_enc2, p.x6p,   nsh);
    gridsync(p.bar + 1, 1024);
    conv_body<32, 64, false, false, 1, 4>(p.x6p,   p.neighs1, p.wb_enc3, p.b_enc3, p.x6,    nsh);
    gridsync(p.bar + 2, 1024);
    conv_body<64, 32, true,  false, 2, 2>(p.x6,    p.neighs2, p.wb_dec1, p.b_dec1, p.x7dec, nsh);
    gridsync(p.bar + 3, 1024);
    conv_body<32, 16, true,  false, 4, 1>(p.x7dec, p.neighs3, p.wb_dec2, p.b_dec2, p.x8dec, nsh);
    gridsync(p.bar + 4, 1024);
    head_body(p, nsh, ws);
}

extern "C" void kernel_launch(void* const* d_in, const int* in_sizes, int n_in,
                              void* d_out, int out_size, void* d_ws, size_t ws_size,
                              hipStream_t stream) {
    Params P;
    P.features = (const float*)d_in[0];
    P.neighs3  = (const int*)d_in[4];
    P.neighs2  = (const int*)d_in[5];
    P.neighs1  = (const int*)d_in[6];
    P.w_enc1 = (const float*)d_in[7];  P.b_enc1 = (const float*)d_in[8];
    P.w_enc2 = (const float*)d_in[9];  P.b_enc2 = (const float*)d_in[10];
    P.w_enc3 = (const float*)d_in[11]; P.b_enc3 = (const float*)d_in[12];
    P.w_dec1 = (const float*)d_in[13]; P.b_dec1 = (const float*)d_in[14];
    P.w_dec2 = (const float*)d_in[15]; P.b_dec2 = (const float*)d_in[16];
    P.w_head = (const float*)d_in[17]; P.b_head = (const float*)d_in[18];

    char* ws = (char*)d_ws;
    size_t off = 0;
    P.wb_enc2 = (unsigned short*)(ws + off); off += 5120 * 2;
    P.wb_enc3 = (unsigned short*)(ws + off); off += 18432 * 2;
    P.wb_dec1 = (unsigned short*)(ws + off); off += 18432 * 2;
    P.wb_dec2 = (unsigned short*)(ws + off); off += 4608 * 2;
    P.x7p   = (unsigned short*)(ws + off); off += (size_t)NN2 * 16 * 2;
    P.x6p   = (unsigned short*)(ws + off); off += (size_t)NN1 * 32 * 2;
    P.x6    = (unsigned short*)(ws + off); off += (size_t)NN1 * 64 * 2;
    P.x7dec = (unsigned short*)(ws + off); off += (size_t)NN2 * 32 * 2;
    P.x8dec = (unsigned short*)(ws + off); off += (size_t)NN3 * 16 * 2;
    off = (off + 255) & ~(size_t)255;
    P.bar   = (unsigned int*)(ws + off);  off += 8 * sizeof(unsigned int);
    P.out = (float*)d_out;

    init_bar<<<1, 64, 0, stream>>>(P.bar);
    fused_kernel<<<1024, 256, 0, stream>>>(P);
}

// Round 6
// 202.915 us; speedup vs baseline: 4.8732x; 4.8732x over previous
//
#include <hip/hip_runtime.h>
#include <stdint.h>

#define NN3 262144
#define NN2 65536
#define NN1 16384

typedef __attribute__((ext_vector_type(8))) __bf16 bf16x8;
typedef __attribute__((ext_vector_type(4))) float floatx4;
typedef __attribute__((ext_vector_type(4))) unsigned int uintx4;

static __device__ __forceinline__ float bf2f(unsigned short u) {
    union { unsigned int i; float f; } v; v.i = ((unsigned int)u) << 16; return v.f;
}
static __device__ __forceinline__ unsigned short f2bf(float f) {
    union { float f; unsigned int i; } v; v.f = f;
    unsigned int x = v.i;
    return (unsigned short)((x + 0x7fffu + ((x >> 16) & 1u)) >> 16);
}
static __device__ __forceinline__ bf16x8 zero_bf16x8() {
    bf16x8 z;
#pragma unroll
    for (int i = 0; i < 8; ++i) z[i] = (__bf16)0.0f;
    return z;
}

// ---------------- swizzled weight prep ----------------
// B in MFMA-fragment order: one coalesced 16B/lane load per (n,kt).
//   out[((n*KT + kt)*64 + lane)*8 + e] = w[(n*16 + m)*K + kt*32 + quad*8 + e]
// k >= K zero-padded (so stale A-fragments at k>=K multiply by 0).
template <int CIN, int COUT>
static __device__ __forceinline__ void prep_swz(const float* __restrict__ w,
                                                unsigned short* __restrict__ out, int g) {
    constexpr int K = 9 * CIN, KT = (K + 31) / 32;
    int n = g / (KT * 512);
    int r = g - n * (KT * 512);
    int kt = r >> 9;
    int q = r & 511;
    int lane = q >> 3, e = q & 7;
    int m = lane & 15, quad = lane >> 4;
    int k = kt * 32 + quad * 8 + e;
    float v = (k < K) ? w[(n * 16 + m) * K + k] : 0.0f;
    out[g] = f2bf(v);
}

// ---------------- enc1 + pool1 fused, with swizzled weight prep folded in ----------------
__global__ __launch_bounds__(256) void enc1pool_kernel(
    const float* __restrict__ feat, const int* __restrict__ neigh,
    const float* __restrict__ w, const float* __restrict__ b,
    unsigned short* __restrict__ x7p,
    const float* __restrict__ w_enc2, const float* __restrict__ w_enc3,
    const float* __restrict__ w_dec1, const float* __restrict__ w_dec2,
    unsigned short* __restrict__ wb_enc2, unsigned short* __restrict__ wb_enc3,
    unsigned short* __restrict__ wb_dec1, unsigned short* __restrict__ wb_dec2)
{
    // folded swizzled weight prep: 46592 elements over the first 182 blocks
    {
        int g = blockIdx.x * 256 + threadIdx.x;
        if (g < 5120) prep_swz<16, 32>(w_enc2, wb_enc2, g);          // NT=2 KT=5
        else {
            g -= 5120;
            if (g < 18432) prep_swz<32, 64>(w_enc3, wb_enc3, g);     // NT=4 KT=9
            else {
                g -= 18432;
                if (g < 18432) prep_swz<64, 32>(w_dec1, wb_dec1, g); // NT=2 KT=18
                else { g -= 18432; if (g < 4608) prep_swz<32, 16>(w_dec2, wb_dec2, g); }
            }
        }
    }
    __shared__ float ws[144];
    __shared__ float bs[16];
    __shared__ int nsh[2304];
    int t = threadIdx.x;
    if (t < 144) ws[t] = w[t];
    if (t < 16)  bs[t] = b[t];
    int base = blockIdx.x * 256;
    for (int e = t; e < 2304; e += 256)
        nsh[e] = __builtin_nontemporal_load(&neigh[(size_t)base * 9 + e]);
    __syncthreads();
    float f[9];
#pragma unroll
    for (int k = 0; k < 9; ++k) { int j = nsh[t * 9 + k]; f[k] = (j < 0) ? 0.0f : feat[j]; }
    float v[16];
#pragma unroll
    for (int co = 0; co < 16; ++co) {
        float a = bs[co];
#pragma unroll
        for (int k = 0; k < 9; ++k) a += f[k] * ws[co * 9 + k];
        v[co] = fmaxf(a, 0.0f);
    }
#pragma unroll
    for (int co = 0; co < 16; ++co) {
        v[co] = fmaxf(v[co], __shfl_xor(v[co], 1));
        v[co] = fmaxf(v[co], __shfl_xor(v[co], 2));
    }
    if ((t & 3) == 0) {
        unsigned int ov[8];
#pragma unroll
        for (int h = 0; h < 8; ++h)
            ov[h] = (unsigned int)f2bf(v[2 * h]) | (((unsigned int)f2bf(v[2 * h + 1])) << 16);
        uintx4* dst = (uintx4*)(x7p + (size_t)((base + t) >> 2) * 16);
        uintx4 o0 = {ov[0], ov[1], ov[2], ov[3]};
        uintx4 o1 = {ov[4], ov[5], ov[6], ov[7]};
        dst[0] = o0;
        dst[1] = o1;
    }
}

// ---------------- generic MFMA conv, 4-deep gather ring ----------------
// The round-6 experiment: per-wave memory-level parallelism. The old pipeline kept
// only TILES gathers in flight (1 kt ahead); the ring keeps PF*TILES = 8-16 loads
// outstanding per wave, testing whether gather service is per-wave-MLP-bound.
// All ring indices are compile-time (full unroll) — no scratch spill (rule #20).
template <int CIN, int COUT, bool SHIFT, bool POOL, int TILES, int WN>
__global__ __launch_bounds__(256) void conv_mfma(
    const unsigned short* __restrict__ src, const int* __restrict__ neigh,
    const unsigned short* __restrict__ wb, const float* __restrict__ bias,
    unsigned short* __restrict__ dst)
{
    constexpr int K   = 9 * CIN;
    constexpr int KT  = (K + 31) / 32;
    constexpr int NT  = COUT / 16;
    constexpr int WM  = 4 / WN;      // wave-groups along rows
    constexpr int NTW = NT / WN;     // couts-of-16 per wave
    constexpr int ROWS = WM * TILES * 16;
    constexpr int PF  = 4;           // ring depth; all instantiations have KT >= 5
    static_assert(KT >= PF, "ring deeper than K-loop");
    __shared__ int nsh[ROWS * 9];
    int t = threadIdx.x;
    int rowbase = blockIdx.x * ROWS;
    for (int e = t; e < ROWS * 9; e += 256) {
        int j = __builtin_nontemporal_load(&neigh[(size_t)rowbase * 9 + e]);
        if (SHIFT) j = (j < 0) ? -1 : (j >> 2);
        nsh[e] = j;
    }
    __syncthreads();
    int lane = t & 63;
    int wave = t >> 6;
    int wm   = wave / WN;
    int wn   = wave - wm * WN;
    int m    = lane & 15;
    int quad = lane >> 4;
    int rbase9[TILES];
#pragma unroll
    for (int tl = 0; tl < TILES; ++tl)
        rbase9[tl] = ((wm * TILES + tl) * 16 + m) * 9;

    floatx4 acc[TILES][NTW];
#pragma unroll
    for (int tl = 0; tl < TILES; ++tl)
#pragma unroll
        for (int n = 0; n < NTW; ++n) acc[tl][n] = (floatx4){0.f, 0.f, 0.f, 0.f};

    auto gatherA = [&](int kt, bf16x8 (&dstA)[TILES]) {
        int k0 = kt * 32 + quad * 8;
#pragma unroll
        for (int tl = 0; tl < TILES; ++tl) {
            dstA[tl] = zero_bf16x8();
            if (k0 < K) {
                int j = nsh[rbase9[tl] + k0 / CIN];
                if (j >= 0) dstA[tl] = *(const bf16x8*)(src + (size_t)j * CIN + (k0 % CIN));
            }
        }
    };

    bf16x8 aB[PF][TILES];
#pragma unroll
    for (int p = 0; p < PF; ++p) gatherA(p, aB[p]);   // fill the ring: PF*TILES loads in flight

#pragma unroll
    for (int kt = 0; kt < KT; ++kt) {
#pragma unroll
        for (int n = 0; n < NTW; ++n) {
            int ng = wn * NTW + n;              // global cout-group
            bf16x8 bfrag = *(const bf16x8*)(wb + ((size_t)(ng * KT + kt) * 64 + lane) * 8);
#pragma unroll
            for (int tl = 0; tl < TILES; ++tl)
                acc[tl][n] = __builtin_amdgcn_mfma_f32_16x16x32_bf16(aB[kt % PF][tl], bfrag, acc[tl][n], 0, 0, 0);
        }
        if (kt + PF < KT) gatherA(kt + PF, aB[kt % PF]);   // refill consumed slot
    }

#pragma unroll
    for (int tl = 0; tl < TILES; ++tl) {
        int rg = wm * TILES + tl;
        if (POOL) {
            int pp = (rowbase >> 2) + rg * 4 + quad;
#pragma unroll
            for (int n = 0; n < NTW; ++n) {
                int cout = (wn * NTW + n) * 16 + m;
                float vm = fmaxf(fmaxf(acc[tl][n][0], acc[tl][n][1]), fmaxf(acc[tl][n][2], acc[tl][n][3]));
                float v  = fmaxf(vm + bias[cout], 0.0f);
                dst[(size_t)pp * COUT + cout] = f2bf(v);
            }
        } else {
            int grow = rowbase + rg * 16 + quad * 4;
#pragma unroll
            for (int n = 0; n < NTW; ++n) {
                int cout = (wn * NTW + n) * 16 + m;
                float bv = bias[cout];
#pragma unroll
                for (int r = 0; r < 4; ++r) {
                    float v = fmaxf(acc[tl][n][r] + bv, 0.0f);
                    dst[(size_t)(grow + r) * COUT + cout] = f2bf(v);
                }
            }
        }
    }
}

// ---------------- head: Cin=16 bf16 -> 1 fp32, no relu ----------------
// Round-6 restructure: 1 row/thread, 4-deep neighbor ring = 8 outstanding 16B
// loads/thread (was 2). j<0 neighbors leave zero-filled registers: accumulation
// is branch-free (dot with 0 contributes 0).
static __device__ __forceinline__ float dot2(unsigned int u, const float* w) {
    return bf2f((unsigned short)(u & 0xffffu)) * w[0] + bf2f((unsigned short)(u >> 16)) * w[1];
}
__global__ __launch_bounds__(256) void head_kernel(
    const unsigned short* __restrict__ x, const int* __restrict__ neigh,
    const float* __restrict__ w, const float* __restrict__ b, float* __restrict__ out)
{
    __shared__ float ws[144];
    __shared__ int nsh[2304];
    int t = threadIdx.x;
    if (t < 144) ws[t] = w[t];
    int base = blockIdx.x * 256;
    for (int e = t; e < 2304; e += 256)
        nsh[e] = __builtin_nontemporal_load(&neigh[(size_t)base * 9 + e]);
    __syncthreads();
    int idx[9];
#pragma unroll
    for (int k = 0; k < 9; ++k) idx[k] = nsh[t * 9 + k];

    uint4 ra[4], rb[4];
    const uint4 z4 = make_uint4(0u, 0u, 0u, 0u);
#pragma unroll
    for (int p = 0; p < 4; ++p) {
        ra[p] = z4; rb[p] = z4;
        int j = idx[p];
        if (j >= 0) {
            const uint4* r = (const uint4*)(x + (size_t)j * 16);
            ra[p] = r[0]; rb[p] = r[1];
        }
    }
    float acc = b[0];
#pragma unroll
    for (int k = 0; k < 9; ++k) {
        const float* wp = &ws[k * 16];
        uint4 r0 = ra[k & 3], r1 = rb[k & 3];
        acc += dot2(r0.x, wp)     + dot2(r0.y, wp + 2)  + dot2(r0.z, wp + 4)  + dot2(r0.w, wp + 6);
        acc += dot2(r1.x, wp + 8) + dot2(r1.y, wp + 10) + dot2(r1.z, wp + 12) + dot2(r1.w, wp + 14);
        if (k + 4 < 9) {
            int j = idx[k + 4];
            ra[k & 3] = z4; rb[k & 3] = z4;
            if (j >= 0) {
                const uint4* r = (const uint4*)(x + (size_t)j * 16);
                ra[k & 3] = r[0]; rb[k & 3] = r[1];
            }
        }
    }
    out[base + t] = acc;
}

extern "C" void kernel_launch(void* const* d_in, const int* in_sizes, int n_in,
                              void* d_out, int out_size, void* d_ws, size_t ws_size,
                              hipStream_t stream) {
    const float* features = (const float*)d_in[0];
    const int* neighs3 = (const int*)d_in[4];
    const int* neighs2 = (const int*)d_in[5];
    const int* neighs1 = (const int*)d_in[6];
    const float* w_enc1 = (const float*)d_in[7];
    const float* b_enc1 = (const float*)d_in[8];
    const float* w_enc2 = (const float*)d_in[9];
    const float* b_enc2 = (const float*)d_in[10];
    const float* w_enc3 = (const float*)d_in[11];
    const float* b_enc3 = (const float*)d_in[12];
    const float* w_dec1 = (const float*)d_in[13];
    const float* b_dec1 = (const float*)d_in[14];
    const float* w_dec2 = (const float*)d_in[15];
    const float* b_dec2 = (const float*)d_in[16];
    const float* w_head = (const float*)d_in[17];
    const float* b_head = (const float*)d_in[18];

    char* ws = (char*)d_ws;
    size_t off = 0;
    unsigned short* wb_enc2 = (unsigned short*)(ws + off); off += 5120 * 2;    // NT*KT*512, kt-padded
    unsigned short* wb_enc3 = (unsigned short*)(ws + off); off += 18432 * 2;
    unsigned short* wb_dec1 = (unsigned short*)(ws + off); off += 18432 * 2;
    unsigned short* wb_dec2 = (unsigned short*)(ws + off); off += 4608 * 2;
    unsigned short* x7p   = (unsigned short*)(ws + off); off += (size_t)NN2 * 16 * 2;
    unsigned short* x6p   = (unsigned short*)(ws + off); off += (size_t)NN1 * 32 * 2;
    unsigned short* x6    = (unsigned short*)(ws + off); off += (size_t)NN1 * 64 * 2;
    unsigned short* x7dec = (unsigned short*)(ws + off); off += (size_t)NN2 * 32 * 2;
    unsigned short* x8dec = (unsigned short*)(ws + off); off += (size_t)NN3 * 16 * 2;

    // 1. enc1 + pool1 (+ folded swizzled weight prep): features -> x7p [N2,16]
    enc1pool_kernel<<<NN3 / 256, 256, 0, stream>>>(features, neighs3, w_enc1, b_enc1, x7p,
                                                   w_enc2, w_enc3, w_dec1, w_dec2,
                                                   wb_enc2, wb_enc3, wb_dec1, wb_dec2);
    // 2. enc2 + pool2: x7p -> x6p [N1,32]   (TILES=2, WN=2)
    conv_mfma<16, 32, false, true, 2, 2><<<NN2 / 64, 256, 0, stream>>>(x7p, neighs2, wb_enc2, b_enc2, x6p);
    // 3. enc3: x6p -> x6 [N1,64]            (TILES=1, WN=4)
    conv_mfma<32, 64, false, false, 1, 4><<<NN1 / 16, 256, 0, stream>>>(x6p, neighs1, wb_enc3, b_enc3, x6);
    // 4. dec1 (fused unpool): x6 -> x7dec [N2,32]   (TILES=2, WN=2)
    conv_mfma<64, 32, true, false, 2, 2><<<NN2 / 64, 256, 0, stream>>>(x6, neighs2, wb_dec1, b_dec1, x7dec);
    // 5. dec2 (fused unpool): x7dec -> x8dec [N3,16]  (TILES=4, WN=1)
    conv_mfma<32, 16, true, false, 4, 1><<<NN3 / 256, 256, 0, stream>>>(x7dec, neighs3, wb_dec2, b_dec2, x8dec);
    // 6. head: x8dec -> out [N3,1]f32       (1 row/thread, ring-4)
    head_kernel<<<NN3 / 256, 256, 0, stream>>>(x8dec, neighs3, w_head, b_head, (float*)d_out);
}